// Round 14
// baseline (1975.766 us; speedup 1.0000x reference)
//
#include <hip/hip_runtime.h>

typedef unsigned short u16;
typedef unsigned int   u32;
typedef __bf16  bf16x8 __attribute__((ext_vector_type(8)));
typedef float   f32x4  __attribute__((ext_vector_type(4)));
typedef u16     u16x4  __attribute__((ext_vector_type(4)));
typedef u16     u16x8  __attribute__((ext_vector_type(8)));

#define HID 2048
#define SEQ 2048
#define BB  4
#define NQH 8
#define HD_ 256
#define INTER_ 8192

__device__ __forceinline__ float b2f(u16 u) {
  union { float f; u32 i; } x; x.i = ((u32)u) << 16; return x.f;
}
__device__ __forceinline__ u16 f2b(float f) {
  u32 u = __float_as_uint(f);
  u32 r = u + 0x7fffu + ((u >> 16) & 1u);
  return (u16)(r >> 16);
}
__device__ __forceinline__ float wsum(float v) {
#pragma unroll
  for (int m = 1; m < 64; m <<= 1) v += __shfl_xor(v, m, 64);
  return v;
}
__device__ __forceinline__ float wmax(float v) {
#pragma unroll
  for (int m = 1; m < 64; m <<= 1) v = fmaxf(v, __shfl_xor(v, m, 64));
  return v;
}
__device__ __forceinline__ void gload_lds16(const void* gp, void* lp) {
  __builtin_amdgcn_global_load_lds(
      (const __attribute__((address_space(1))) void*)gp,
      (__attribute__((address_space(3))) void*)lp, 16, 0, 0);
}
// XCD-aware block swizzle (nwg % 8 == 0 on all our grids)
__device__ __forceinline__ void xcd_swizzle(int& bx, int& by) {
  const int nx = gridDim.x, ny = gridDim.y;
  const int nwg = nx * ny;
  if ((nwg & 7) == 0) {
    const int orig = by * nx + bx;
    const int q = nwg >> 3;
    const int wg = (orig & 7) * q + (orig >> 3);
    bx = wg % nx; by = wg / nx;
  }
}

// ---------------------------------------------------------------- fp32 -> bf16 convert
__global__ __launch_bounds__(256) void cvt_kernel(const float* __restrict__ src,
                                                  u16* __restrict__ dst, int n4) {
  int i = blockIdx.x * 256 + threadIdx.x;
  if (i < n4) {
    const float4 v = *(const float4*)(src + (size_t)i * 4);
    u16x4 o;
    o[0] = f2b(v.x); o[1] = f2b(v.y); o[2] = f2b(v.z); o[3] = f2b(v.w);
    *(u16x4*)(dst + (size_t)i * 4) = o;
  }
}

// ---------------------------------------------------------------- sfac[b][n] = w[n]*(1 + dot(t[b], tw[n]))
__global__ __launch_bounds__(256) void scale_kernel(
    const float* __restrict__ temb,
    const float* __restrict__ w1, const float* __restrict__ tw1,
    const float* __restrict__ w2, const float* __restrict__ tw2,
    float* __restrict__ sf1, float* __restrict__ sf2) {
  const int wave = threadIdx.x >> 6, lane = threadIdx.x & 63;
  const int o = blockIdx.x * 4 + wave;
  const int set = o / (BB * HID);
  const int r = o % (BB * HID);
  const int b = r / HID, n = r % HID;
  const float* tw = set ? tw2 : tw1;
  const float* w  = set ? w2  : w1;
  float* sf       = set ? sf2 : sf1;
  const float* tv  = temb + (size_t)b * HID;
  const float* twr = tw + (size_t)n * HID;
  float acc = 0.f;
#pragma unroll
  for (int q = 0; q < 8; ++q) {
    const float4 a = *(const float4*)(tv + q * 256 + lane * 4);
    const float4 c = *(const float4*)(twr + q * 256 + lane * 4);
    acc += a.x * c.x + a.y * c.y + a.z * c.z + a.w * c.w;
  }
  acc = wsum(acc);
  if (lane == 0) sf[(size_t)b * HID + n] = w[n] * (1.0f + acc);
}

// ---------------------------------------------------------------- rope tables
__global__ __launch_bounds__(256) void rope_table_kernel(const int* __restrict__ pos_ids,
                                                         float* __restrict__ cosT,
                                                         float* __restrict__ sinT) {
  const int idx = blockIdx.x * 256 + threadIdx.x;   // B*S*128
  const int j = idx & 127, bs = idx >> 7;
  const float pos = (float)pos_ids[bs];
  const float inv = exp2f(-(float)j * (13.287712379549449f / 128.0f)); // 10000^{-j/128}
  const float ang = pos * inv;
  float sv, cv;
  sincosf(ang, &sv, &cv);
  cosT[idx] = cv; sinT[idx] = sv;
}

// ---------------------------------------------------------------- AdaRMS: bf16 out = fp32 in * rsqrt(mean sq) * sfac
__global__ __launch_bounds__(256) void rmsnorm_kernel(const float* __restrict__ xin,
                                                      const float* __restrict__ sfac,
                                                      u16* __restrict__ out) {
  const int row = blockIdx.x;
  const int b = row >> 11;
  const float* xr = xin + (size_t)row * HID + threadIdx.x * 8;
  const float4 v0 = *(const float4*)(xr);
  const float4 v1 = *(const float4*)(xr + 4);
  float v[8] = {v0.x, v0.y, v0.z, v0.w, v1.x, v1.y, v1.z, v1.w};
  float ss = 0.f;
#pragma unroll
  for (int j = 0; j < 8; ++j) ss += v[j] * v[j];
  ss = wsum(ss);
  __shared__ float red[4];
  const int wave = threadIdx.x >> 6, lane = threadIdx.x & 63;
  if (lane == 0) red[wave] = ss;
  __syncthreads();
  const float tot = red[0] + red[1] + red[2] + red[3];
  const float rs = rsqrtf(tot * (1.0f / HID) + 1e-6f);
  const float* sf = sfac + (size_t)b * HID + threadIdx.x * 8;
  u16* op = out + (size_t)row * HID + threadIdx.x * 8;
  u16x8 o;
#pragma unroll
  for (int j = 0; j < 8; ++j) o[j] = f2b(v[j] * rs * sf[j]);
  *(u16x8*)op = o;
}

// ---------------------------------------------------------------- MFMA GEMM: C(MxN) = A(MxK) @ B(NxK)^T, bf16 in, fp32 acc
// 128x128 tile, BK=32, 4 waves (2x2). DEPTH-2 pipeline: 3 LDS buffers,
// counted s_waitcnt vmcnt(4) + raw s_barrier (loads stay in flight across barriers).
// LDS unit-swizzle: slot (row, s) holds global 16B-unit s ^ ((row>>1)&3)
// (pre-swizzled gload SOURCE + swizzled ds_read addr; LDS dest stays linear).
// XCD-aware block swizzle. blockIdx.z offsets A by aZ, C by cZ elements. Requires K >= 64.
// EPI: 0 = bf16 store; 1 = bf16 C := silu(C_old)*acc (in place);
//      2 = FP32 store acc + Res_f32[idx]; 3 = FP32 C := acc + C_old (in place residual)
template <int EPI>
__global__ __launch_bounds__(256) void gemm_bt(const u16* __restrict__ A,
                                               const u16* __restrict__ B,
                                               const float* __restrict__ Res,
                                               void* __restrict__ Cv,
                                               int K, int lda, int ldb, int ldc,
                                               size_t aZ, size_t cZ) {
  A += blockIdx.z * aZ;
  __shared__ u16 As[3][128 * 32];
  __shared__ u16 Bs[3][128 * 32];
  int bx = blockIdx.x, by = blockIdx.y;
  xcd_swizzle(bx, by);
  const int m0 = bx * 128, n0 = by * 128;
  const int wave = threadIdx.x >> 6, lane = threadIdx.x & 63;
  const int wr = wave >> 1, wc = wave & 1;
  const int l15 = lane & 15, l4 = lane >> 4;

  // staging geometry (per-thread constants)
  const int c0 = threadIdx.x,        r0 = c0 >> 2, u0 = c0 & 3;
  const int c1 = threadIdx.x + 256,  r1 = c1 >> 2, u1 = c1 & 3;
  const int s0 = (u0 ^ ((r0 >> 1) & 3)) << 3;   // pre-swizzled source col (u16 units)
  const int s1 = (u1 ^ ((r1 >> 1) & 3)) << 3;

  auto stage = [&](int buf, int kt) {
    gload_lds16(A + (size_t)(m0 + r0) * lda + kt + s0, &As[buf][c0 * 8]);
    gload_lds16(B + (size_t)(n0 + r0) * ldb + kt + s0, &Bs[buf][c0 * 8]);
    gload_lds16(A + (size_t)(m0 + r1) * lda + kt + s1, &As[buf][c1 * 8]);
    gload_lds16(B + (size_t)(n0 + r1) * ldb + kt + s1, &Bs[buf][c1 * 8]);
  };

  f32x4 acc[4][4] = {};

  stage(0, 0);
  stage(1, 32);
  int cur = 0;
  for (int kt = 0; kt < K; kt += 32) {
    if (kt + 32 < K) {
      asm volatile("s_waitcnt vmcnt(4)" ::: "memory");   // stage(t) done; stage(t+1) in flight
    } else {
      asm volatile("s_waitcnt vmcnt(0)" ::: "memory");   // last tile: drain
    }
    __builtin_amdgcn_s_barrier();
    if (kt + 64 < K) {
      const int nxt = (cur == 0) ? 2 : cur - 1;          // (cur+2)%3
      stage(nxt, kt + 64);
    }
    bf16x8 af[4], bf[4];
#pragma unroll
    for (int ms = 0; ms < 4; ++ms) {
      const int r = wr * 64 + ms * 16 + l15;
      af[ms] = *(const bf16x8*)(&As[cur][r * 32 + ((l4 ^ ((r >> 1) & 3)) << 3)]);
    }
#pragma unroll
    for (int ns = 0; ns < 4; ++ns) {
      const int r = wc * 64 + ns * 16 + l15;
      bf[ns] = *(const bf16x8*)(&Bs[cur][r * 32 + ((l4 ^ ((r >> 1) & 3)) << 3)]);
    }
#pragma unroll
    for (int ms = 0; ms < 4; ++ms)
#pragma unroll
      for (int ns = 0; ns < 4; ++ns)
        acc[ms][ns] = __builtin_amdgcn_mfma_f32_16x16x32_bf16(af[ms], bf[ns], acc[ms][ns], 0, 0, 0);
    cur = (cur == 2) ? 0 : cur + 1;
  }

  u16* Cb = (u16*)Cv + blockIdx.z * cZ;
  float* Cf = (float*)Cv + blockIdx.z * cZ;
#pragma unroll
  for (int ms = 0; ms < 4; ++ms)
#pragma unroll
    for (int i = 0; i < 4; ++i) {
      const int row = m0 + wr * 64 + ms * 16 + l4 * 4 + i;
#pragma unroll
      for (int ns = 0; ns < 4; ++ns) {
        const int col = n0 + wc * 64 + ns * 16 + l15;
        const size_t idx = (size_t)row * ldc + col;
        const float v = acc[ms][ns][i];
        if constexpr (EPI == 0) {
          Cb[idx] = f2b(v);
        } else if constexpr (EPI == 1) {
          const float g = b2f(Cb[idx]);
          Cb[idx] = f2b(g / (1.0f + __expf(-g)) * v);
        } else if constexpr (EPI == 2) {
          Cf[idx] = v + Res[idx];
        } else {
          Cf[idx] = v + Cf[idx];
        }
      }
    }
}

// ---------------------------------------------------------------- RoPE in place (q scaled 1/16) + V transpose -> vt (b,d,s)
__global__ __launch_bounds__(256) void rope_apply_kernel(u16* __restrict__ qkv,
                                                         const float* __restrict__ cosT,
                                                         const float* __restrict__ sinT,
                                                         u16* __restrict__ vt) {
  const int tok = blockIdx.x;
  const int b = tok >> 11, s = tok & 2047;
  u16* rowp = qkv + (size_t)tok * 2560;
  const float* ct = cosT + (size_t)tok * 128;
  const float* st = sinT + (size_t)tok * 128;
  for (int p = threadIdx.x; p < 1024; p += 256) {
    const int h = p >> 7, j = p & 127;
    u16* e = rowp + h * 256 + j;
    const float x1 = b2f(e[0]), x2 = b2f(e[128]);
    const float c = ct[j], sn = st[j];
    e[0]   = f2b((x1 * c - x2 * sn) * 0.0625f);
    e[128] = f2b((x2 * c + x1 * sn) * 0.0625f);
  }
  if (threadIdx.x < 128) {
    const int j = threadIdx.x;
    u16* e = rowp + 2048 + j;
    const float x1 = b2f(e[0]), x2 = b2f(e[128]);
    const float c = ct[j], sn = st[j];
    e[0]   = f2b(x1 * c - x2 * sn);
    e[128] = f2b(x2 * c + x1 * sn);
  }
  {
    const int d = threadIdx.x;
    vt[((size_t)b * HD_ + d) * SEQ + s] = rowp[2304 + d];
  }
}

// ---------------------------------------------------------------- row softmax, in place, 2048-wide bf16 rows
__global__ __launch_bounds__(256) void softmax_kernel(u16* __restrict__ Sb) {
  const int row = blockIdx.x;
  u16* rp = Sb + (size_t)row * 2048 + threadIdx.x * 8;
  const u16x8 t = *(const u16x8*)rp;
  float v[8];
#pragma unroll
  for (int j = 0; j < 8; ++j) v[j] = b2f(t[j]);
  float m = v[0];
#pragma unroll
  for (int j = 1; j < 8; ++j) m = fmaxf(m, v[j]);
  m = wmax(m);
  __shared__ float redm[4], reds[4];
  const int wave = threadIdx.x >> 6, lane = threadIdx.x & 63;
  if (lane == 0) redm[wave] = m;
  __syncthreads();
  m = fmaxf(fmaxf(redm[0], redm[1]), fmaxf(redm[2], redm[3]));
  float s = 0.f;
#pragma unroll
  for (int j = 0; j < 8; ++j) { v[j] = __expf(v[j] - m); s += v[j]; }
  s = wsum(s);
  if (lane == 0) reds[wave] = s;
  __syncthreads();
  const float inv = 1.0f / (reds[0] + reds[1] + reds[2] + reds[3]);
  u16x8 o;
#pragma unroll
  for (int j = 0; j < 8; ++j) o[j] = f2b(v[j] * inv);
  *(u16x8*)rp = o;
}

// ---------------------------------------------------------------- launch
extern "C" void kernel_launch(void* const* d_in, const int* in_sizes, int n_in,
                              void* d_out, int out_size, void* d_ws, size_t ws_size,
                              hipStream_t stream) {
  const float* x     = (const float*)d_in[0];
  const int*   pos   = (const int*)d_in[1];
  const float* temb  = (const float*)d_in[2];
  const float* ln1w  = (const float*)d_in[3];
  const float* ln1tw = (const float*)d_in[4];
  const float* ln2w  = (const float*)d_in[5];
  const float* ln2tw = (const float*)d_in[6];
  const float* Wq    = (const float*)d_in[7];
  const float* Wk    = (const float*)d_in[8];
  const float* Wv    = (const float*)d_in[9];
  const float* Wo    = (const float*)d_in[10];
  const float* Wg    = (const float*)d_in[11];
  const float* Wu    = (const float*)d_in[12];
  const float* Wd    = (const float*)d_in[13];
  float* out = (float*)d_out;      // fp32 output

  char* ws = (char*)d_ws;
  // ---- workspace layout (bytes); REQUIRED = 241,238,016 (230.06 MiB, proven)
  constexpr size_t OFF_SF1  = 0;
  constexpr size_t OFF_SF2  = 32768;
  constexpr size_t OFF_COS  = 65536;
  constexpr size_t OFF_SIN  = 4259840;
  constexpr size_t OFF_WQKV = 8454144;
  constexpr size_t OFF_WO   = 18939904;
  constexpr size_t OFF_WG   = 27328512;
  constexpr size_t OFF_WU   = 60882944;
  constexpr size_t OFF_WD   = 94437376;
  constexpr size_t OFF_H    = 127991808;
  constexpr size_t OFF_QKV  = 161546240;   // MLP phase: inter (67.1MB, M=4096 chunk) aliases qkv+vt+ctx
  constexpr size_t OFF_VT   = 203489280;
  constexpr size_t OFF_CTX  = 207683584;
  constexpr size_t REQUIRED = 241238016;

  float* sf1 = (float*)(ws + OFF_SF1);
  float* sf2 = (float*)(ws + OFF_SF2);
  float* cosT = (float*)(ws + OFF_COS);
  float* sinT = (float*)(ws + OFF_SIN);
  u16* wqkv = (u16*)(ws + OFF_WQKV);
  u16* wo   = (u16*)(ws + OFF_WO);
  u16* wg   = (u16*)(ws + OFF_WG);
  u16* wu   = (u16*)(ws + OFF_WU);
  u16* wd   = (u16*)(ws + OFF_WD);
  u16* hbuf = (u16*)(ws + OFF_H);
  u16* qkv  = (u16*)(ws + OFF_QKV);
  u16* vt   = (u16*)(ws + OFF_VT);
  u16* ctx  = (u16*)(ws + OFF_CTX);
  u16* inter = (u16*)(ws + OFF_QKV);       // 4096 x 8192 bf16 chunk
  u16* Sbuf = (u16*)d_out;                 // d_out (67.1 MB) dead until step 6

  if (ws_size < REQUIRED) return;

  auto cvt = [&](const float* s, u16* d, size_t n) {
    int n4 = (int)(n / 4);
    cvt_kernel<<<(n4 + 255) / 256, 256, 0, stream>>>(s, d, n4);
  };

  // 0) all weights -> bf16 once
  cvt(Wq, wqkv,                      (size_t)2048 * HID);
  cvt(Wk, wqkv + (size_t)2048 * HID, (size_t)256 * HID);
  cvt(Wv, wqkv + (size_t)2304 * HID, (size_t)256 * HID);
  cvt(Wo, wo, (size_t)HID * HID);
  cvt(Wg, wg, (size_t)INTER_ * HID);
  cvt(Wu, wu, (size_t)INTER_ * HID);
  cvt(Wd, wd, (size_t)HID * INTER_);

  // 1) adaptive scales + rope tables
  scale_kernel<<<(2 * BB * HID) / 4, 256, 0, stream>>>(temb, ln1w, ln1tw, ln2w, ln2tw, sf1, sf2);
  rope_table_kernel<<<(BB * SEQ * 128) / 256, 256, 0, stream>>>(pos, cosT, sinT);

  // 2) norm1 -> h (bf16)
  rmsnorm_kernel<<<BB * SEQ, 256, 0, stream>>>(x, sf1, hbuf);

  // 3) qkv = h @ Wqkv^T
  gemm_bt<0><<<dim3(64, 20), 256, 0, stream>>>(hbuf, wqkv, nullptr, qkv, HID, HID, HID, 2560, 0, 0);

  // 4) rope in place (q scaled 1/16), v -> vt
  rope_apply_kernel<<<BB * SEQ, 256, 0, stream>>>(qkv, cosT, sinT, vt);

  // 5) attention per batch: all 8 heads per launch (Sbuf = d_out scratch)
  for (int b = 0; b < BB; ++b) {
    const u16* qb = qkv + (size_t)b * SEQ * 2560;          // head h at +h*256
    const u16* kb = qb + 2048;
    const u16* vb = vt + (size_t)b * HD_ * SEQ;
    u16* cb = ctx + (size_t)b * SEQ * HID;                 // head h at +h*256
    gemm_bt<0><<<dim3(16, 16, 8), 256, 0, stream>>>(
        qb, kb, nullptr, Sbuf, HD_, 2560, 2560, SEQ, (size_t)HD_, (size_t)SEQ * SEQ);
    softmax_kernel<<<NQH * SEQ, 256, 0, stream>>>(Sbuf);
    gemm_bt<0><<<dim3(16, 2, 8), 256, 0, stream>>>(
        Sbuf, vb, nullptr, cb, SEQ, SEQ, SEQ, HID, (size_t)SEQ * SEQ, (size_t)HD_);
  }

  // 6) x2 = ctx @ Wo^T + x -> out (fp32, full overwrite of the Sbuf scratch)
  gemm_bt<2><<<dim3(64, 16), 256, 0, stream>>>(ctx, wo, x, out, HID, HID, HID, HID, 0, 0);

  // 7) norm2 -> h (reads fp32 x2)
  rmsnorm_kernel<<<BB * SEQ, 256, 0, stream>>>(out, sf2, hbuf);

  // 8) MLP, 2 chunks of M=4096 (inter aliases dead qkv/vt/ctx)
  constexpr int MC = BB * SEQ / 2;   // 4096
  for (int c = 0; c < 2; ++c) {
    const u16* hA = hbuf + (size_t)c * MC * HID;
    float* outC = out + (size_t)c * MC * HID;
    gemm_bt<0><<<dim3(MC / 128, INTER_ / 128), 256, 0, stream>>>(hA, wg, nullptr, inter, HID, HID, HID, INTER_, 0, 0);
    gemm_bt<1><<<dim3(MC / 128, INTER_ / 128), 256, 0, stream>>>(hA, wu, nullptr, inter, HID, HID, HID, INTER_, 0, 0);
    gemm_bt<3><<<dim3(MC / 128, HID / 128),    256, 0, stream>>>(inter, wd, nullptr, outC, INTER_, INTER_, INTER_, HID, 0, 0);
  }

  (void)in_sizes; (void)n_in; (void)out_size;
}

// Round 15
// 1731.761 us; speedup vs baseline: 1.1409x; 1.1409x over previous
//
#include <hip/hip_runtime.h>

typedef unsigned short u16;
typedef unsigned int   u32;
typedef __bf16  bf16x8 __attribute__((ext_vector_type(8)));
typedef float   f32x4  __attribute__((ext_vector_type(4)));
typedef u16     u16x4  __attribute__((ext_vector_type(4)));
typedef u16     u16x8  __attribute__((ext_vector_type(8)));

#define HID 2048
#define SEQ 2048
#define BB  4
#define NQH 8
#define HD_ 256
#define INTER_ 8192

__device__ __forceinline__ float b2f(u16 u) {
  union { float f; u32 i; } x; x.i = ((u32)u) << 16; return x.f;
}
__device__ __forceinline__ u16 f2b(float f) {
  u32 u = __float_as_uint(f);
  u32 r = u + 0x7fffu + ((u >> 16) & 1u);
  return (u16)(r >> 16);
}
__device__ __forceinline__ float wsum(float v) {
#pragma unroll
  for (int m = 1; m < 64; m <<= 1) v += __shfl_xor(v, m, 64);
  return v;
}
__device__ __forceinline__ float wmax(float v) {
#pragma unroll
  for (int m = 1; m < 64; m <<= 1) v = fmaxf(v, __shfl_xor(v, m, 64));
  return v;
}
__device__ __forceinline__ void gload_lds16(const void* gp, void* lp) {
  __builtin_amdgcn_global_load_lds(
      (const __attribute__((address_space(1))) void*)gp,
      (__attribute__((address_space(3))) void*)lp, 16, 0, 0);
}
// XCD-aware block swizzle (nwg % 8 == 0 on all our grids)
__device__ __forceinline__ void xcd_swizzle(int& bx, int& by) {
  const int nx = gridDim.x, ny = gridDim.y;
  const int nwg = nx * ny;
  if ((nwg & 7) == 0) {
    const int orig = by * nx + bx;
    const int q = nwg >> 3;
    const int wg = (orig & 7) * q + (orig >> 3);
    bx = wg % nx; by = wg / nx;
  }
}

// ---------------------------------------------------------------- fp32 -> bf16 convert
__global__ __launch_bounds__(256) void cvt_kernel(const float* __restrict__ src,
                                                  u16* __restrict__ dst, int n4) {
  int i = blockIdx.x * 256 + threadIdx.x;
  if (i < n4) {
    const float4 v = *(const float4*)(src + (size_t)i * 4);
    u16x4 o;
    o[0] = f2b(v.x); o[1] = f2b(v.y); o[2] = f2b(v.z); o[3] = f2b(v.w);
    *(u16x4*)(dst + (size_t)i * 4) = o;
  }
}

// ---------------------------------------------------------------- sfac[b][n] = w[n]*(1 + dot(t[b], tw[n]))
__global__ __launch_bounds__(256) void scale_kernel(
    const float* __restrict__ temb,
    const float* __restrict__ w1, const float* __restrict__ tw1,
    const float* __restrict__ w2, const float* __restrict__ tw2,
    float* __restrict__ sf1, float* __restrict__ sf2) {
  const int wave = threadIdx.x >> 6, lane = threadIdx.x & 63;
  const int o = blockIdx.x * 4 + wave;
  const int set = o / (BB * HID);
  const int r = o % (BB * HID);
  const int b = r / HID, n = r % HID;
  const float* tw = set ? tw2 : tw1;
  const float* w  = set ? w2  : w1;
  float* sf       = set ? sf2 : sf1;
  const float* tv  = temb + (size_t)b * HID;
  const float* twr = tw + (size_t)n * HID;
  float acc = 0.f;
#pragma unroll
  for (int q = 0; q < 8; ++q) {
    const float4 a = *(const float4*)(tv + q * 256 + lane * 4);
    const float4 c = *(const float4*)(twr + q * 256 + lane * 4);
    acc += a.x * c.x + a.y * c.y + a.z * c.z + a.w * c.w;
  }
  acc = wsum(acc);
  if (lane == 0) sf[(size_t)b * HID + n] = w[n] * (1.0f + acc);
}

// ---------------------------------------------------------------- rope tables
__global__ __launch_bounds__(256) void rope_table_kernel(const int* __restrict__ pos_ids,
                                                         float* __restrict__ cosT,
                                                         float* __restrict__ sinT) {
  const int idx = blockIdx.x * 256 + threadIdx.x;   // B*S*128
  const int j = idx & 127, bs = idx >> 7;
  const float pos = (float)pos_ids[bs];
  const float inv = exp2f(-(float)j * (13.287712379549449f / 128.0f)); // 10000^{-j/128}
  const float ang = pos * inv;
  float sv, cv;
  sincosf(ang, &sv, &cv);
  cosT[idx] = cv; sinT[idx] = sv;
}

// ---------------------------------------------------------------- AdaRMS: bf16 out = fp32 in * rsqrt(mean sq) * sfac
__global__ __launch_bounds__(256) void rmsnorm_kernel(const float* __restrict__ xin,
                                                      const float* __restrict__ sfac,
                                                      u16* __restrict__ out) {
  const int row = blockIdx.x;
  const int b = row >> 11;
  const float* xr = xin + (size_t)row * HID + threadIdx.x * 8;
  const float4 v0 = *(const float4*)(xr);
  const float4 v1 = *(const float4*)(xr + 4);
  float v[8] = {v0.x, v0.y, v0.z, v0.w, v1.x, v1.y, v1.z, v1.w};
  float ss = 0.f;
#pragma unroll
  for (int j = 0; j < 8; ++j) ss += v[j] * v[j];
  ss = wsum(ss);
  __shared__ float red[4];
  const int wave = threadIdx.x >> 6, lane = threadIdx.x & 63;
  if (lane == 0) red[wave] = ss;
  __syncthreads();
  const float tot = red[0] + red[1] + red[2] + red[3];
  const float rs = rsqrtf(tot * (1.0f / HID) + 1e-6f);
  const float* sf = sfac + (size_t)b * HID + threadIdx.x * 8;
  u16* op = out + (size_t)row * HID + threadIdx.x * 8;
  u16x8 o;
#pragma unroll
  for (int j = 0; j < 8; ++j) o[j] = f2b(v[j] * rs * sf[j]);
  *(u16x8*)op = o;
}

// ---------------------------------------------------------------- 256^2-tile MFMA GEMM (8 waves, BK=64, counted vmcnt)
// C(MxN) = A(MxK) @ B(NxK)^T, bf16 in, fp32 acc. M,N % 256 == 0, K % 64 == 0, K >= 128.
// Per K-tile: two k-half phases; each {12 ds_read_b128; stage 2 half-tiles of t+1;
// setprio(1); 32 MFMA; setprio(0)}; sync = vmcnt(4) + raw s_barrier (2x per K-tile).
// LDS 128KB (2 dbuf x 2 khalf x [256][32] x A,B). Unit swizzle cu' = cu ^ ((row>>1)&3).
// EPI: 0 = bf16 store; 1 = bf16 C := silu(C_old)*acc; 2 = FP32 store acc + Res_f32[idx]
template <int EPI>
__global__ __launch_bounds__(512, 2) void gemm256(const u16* __restrict__ A,
                                                  const u16* __restrict__ B,
                                                  const float* __restrict__ Res,
                                                  void* __restrict__ Cv,
                                                  int K, int lda, int ldb, int ldc) {
  __shared__ u16 As[2 * 2 * 8192];
  __shared__ u16 Bs[2 * 2 * 8192];
  int bx = blockIdx.x, by = blockIdx.y;
  xcd_swizzle(bx, by);
  const int m0 = bx * 256, n0 = by * 256;
  const int w = threadIdx.x >> 6, lane = threadIdx.x & 63;
  const int wr = w >> 2, wcn = w & 3;          // 2 x 4 wave grid
  const int l15 = lane & 15, l4 = lane >> 4;

  // staging geometry: each k-half tile = 256 rows x 32 cols = 1024 x 16B units
  const int u0 = threadIdx.x, u1 = threadIdx.x + 512;
  const int r0 = u0 >> 2, q0 = u0 & 3, s0 = (q0 ^ ((r0 >> 1) & 3)) * 8;
  const int r1 = u1 >> 2, q1 = u1 & 3, s1 = (q1 ^ ((r1 >> 1) & 3)) * 8;

  auto stageA = [&](int buf, int ks, int kt) {
    u16* lp = &As[(buf * 2 + ks) * 8192];
    gload_lds16(A + (size_t)(m0 + r0) * lda + kt + ks * 32 + s0, lp + u0 * 8);
    gload_lds16(A + (size_t)(m0 + r1) * lda + kt + ks * 32 + s1, lp + u1 * 8);
  };
  auto stageB = [&](int buf, int ks, int kt) {
    u16* lp = &Bs[(buf * 2 + ks) * 8192];
    gload_lds16(B + (size_t)(n0 + r0) * ldb + kt + ks * 32 + s0, lp + u0 * 8);
    gload_lds16(B + (size_t)(n0 + r1) * ldb + kt + ks * 32 + s1, lp + u1 * 8);
  };

  f32x4 acc[8][4] = {};

  // prologue: tile 0 fully staged (order: A-k0, B-k0, A-k1, B-k1)
  stageA(0, 0, 0); stageB(0, 0, 0); stageA(0, 1, 0); stageB(0, 1, 0);

  const int T = K >> 6;
  for (int t = 0; t < T; ++t) {
    const int cur = t & 1, kt = t * 64;
    const bool more = (t + 1 < T);
#pragma unroll
    for (int ks = 0; ks < 2; ++ks) {
      // sync: this k-half's A/B landed (all waves); keep newer halves in flight
      if (more || ks == 0) asm volatile("s_waitcnt vmcnt(4)" ::: "memory");
      else                 asm volatile("s_waitcnt vmcnt(0)" ::: "memory");
      __builtin_amdgcn_s_barrier();
      asm volatile("" ::: "memory");
      const u16* la = &As[(cur * 2 + ks) * 8192];
      const u16* lb = &Bs[(cur * 2 + ks) * 8192];
      bf16x8 af[8], bf[4];
#pragma unroll
      for (int mr = 0; mr < 8; ++mr) {
        const int r = wr * 128 + mr * 16 + l15;
        af[mr] = *(const bf16x8*)(la + r * 32 + ((l4 ^ ((r >> 1) & 3)) * 8));
      }
#pragma unroll
      for (int nr = 0; nr < 4; ++nr) {
        const int r = wcn * 64 + nr * 16 + l15;
        bf[nr] = *(const bf16x8*)(lb + r * 32 + ((l4 ^ ((r >> 1) & 3)) * 8));
      }
      if (more) { stageA(cur ^ 1, ks, kt + 64); stageB(cur ^ 1, ks, kt + 64); }
      __builtin_amdgcn_s_setprio(1);
#pragma unroll
      for (int mr = 0; mr < 8; ++mr)
#pragma unroll
        for (int nr = 0; nr < 4; ++nr)
          acc[mr][nr] = __builtin_amdgcn_mfma_f32_16x16x32_bf16(af[mr], bf[nr], acc[mr][nr], 0, 0, 0);
      __builtin_amdgcn_s_setprio(0);
    }
  }

  u16* Cb = (u16*)Cv;
  float* Cf = (float*)Cv;
#pragma unroll
  for (int mr = 0; mr < 8; ++mr)
#pragma unroll
    for (int i = 0; i < 4; ++i) {
      const int row = m0 + wr * 128 + mr * 16 + l4 * 4 + i;
#pragma unroll
      for (int nr = 0; nr < 4; ++nr) {
        const int col = n0 + wcn * 64 + nr * 16 + l15;
        const size_t idx = (size_t)row * ldc + col;
        const float v = acc[mr][nr][i];
        if constexpr (EPI == 0) {
          Cb[idx] = f2b(v);
        } else if constexpr (EPI == 1) {
          const float g = b2f(Cb[idx]);
          Cb[idx] = f2b(g / (1.0f + __expf(-g)) * v);
        } else {
          Cf[idx] = v + Res[idx];
        }
      }
    }
}

// ---------------------------------------------------------------- 128^2 MFMA GEMM (R14 structure, kept for attention + down-proj)
template <int EPI>
__global__ __launch_bounds__(256) void gemm_bt(const u16* __restrict__ A,
                                               const u16* __restrict__ B,
                                               const float* __restrict__ Res,
                                               void* __restrict__ Cv,
                                               int K, int lda, int ldb, int ldc,
                                               size_t aZ, size_t cZ) {
  A += blockIdx.z * aZ;
  __shared__ u16 As[3][128 * 32];
  __shared__ u16 Bs[3][128 * 32];
  int bx = blockIdx.x, by = blockIdx.y;
  xcd_swizzle(bx, by);
  const int m0 = bx * 128, n0 = by * 128;
  const int wave = threadIdx.x >> 6, lane = threadIdx.x & 63;
  const int wr = wave >> 1, wc = wave & 1;
  const int l15 = lane & 15, l4 = lane >> 4;

  const int c0 = threadIdx.x,        r0 = c0 >> 2, u0 = c0 & 3;
  const int c1 = threadIdx.x + 256,  r1 = c1 >> 2, u1 = c1 & 3;
  const int s0 = (u0 ^ ((r0 >> 1) & 3)) << 3;
  const int s1 = (u1 ^ ((r1 >> 1) & 3)) << 3;

  auto stage = [&](int buf, int kt) {
    gload_lds16(A + (size_t)(m0 + r0) * lda + kt + s0, &As[buf][c0 * 8]);
    gload_lds16(B + (size_t)(n0 + r0) * ldb + kt + s0, &Bs[buf][c0 * 8]);
    gload_lds16(A + (size_t)(m0 + r1) * lda + kt + s1, &As[buf][c1 * 8]);
    gload_lds16(B + (size_t)(n0 + r1) * ldb + kt + s1, &Bs[buf][c1 * 8]);
  };

  f32x4 acc[4][4] = {};

  stage(0, 0);
  stage(1, 32);
  int cur = 0;
  for (int kt = 0; kt < K; kt += 32) {
    if (kt + 32 < K) {
      asm volatile("s_waitcnt vmcnt(4)" ::: "memory");
    } else {
      asm volatile("s_waitcnt vmcnt(0)" ::: "memory");
    }
    __builtin_amdgcn_s_barrier();
    if (kt + 64 < K) {
      const int nxt = (cur == 0) ? 2 : cur - 1;
      stage(nxt, kt + 64);
    }
    bf16x8 af[4], bf[4];
#pragma unroll
    for (int ms = 0; ms < 4; ++ms) {
      const int r = wr * 64 + ms * 16 + l15;
      af[ms] = *(const bf16x8*)(&As[cur][r * 32 + ((l4 ^ ((r >> 1) & 3)) << 3)]);
    }
#pragma unroll
    for (int ns = 0; ns < 4; ++ns) {
      const int r = wc * 64 + ns * 16 + l15;
      bf[ns] = *(const bf16x8*)(&Bs[cur][r * 32 + ((l4 ^ ((r >> 1) & 3)) << 3)]);
    }
#pragma unroll
    for (int ms = 0; ms < 4; ++ms)
#pragma unroll
      for (int ns = 0; ns < 4; ++ns)
        acc[ms][ns] = __builtin_amdgcn_mfma_f32_16x16x32_bf16(af[ms], bf[ns], acc[ms][ns], 0, 0, 0);
    cur = (cur == 2) ? 0 : cur + 1;
  }

  u16* Cb = (u16*)Cv + blockIdx.z * cZ;
  float* Cf = (float*)Cv + blockIdx.z * cZ;
#pragma unroll
  for (int ms = 0; ms < 4; ++ms)
#pragma unroll
    for (int i = 0; i < 4; ++i) {
      const int row = m0 + wr * 64 + ms * 16 + l4 * 4 + i;
#pragma unroll
      for (int ns = 0; ns < 4; ++ns) {
        const int col = n0 + wc * 64 + ns * 16 + l15;
        const size_t idx = (size_t)row * ldc + col;
        const float v = acc[ms][ns][i];
        if constexpr (EPI == 0) {
          Cb[idx] = f2b(v);
        } else if constexpr (EPI == 1) {
          const float g = b2f(Cb[idx]);
          Cb[idx] = f2b(g / (1.0f + __expf(-g)) * v);
        } else if constexpr (EPI == 2) {
          Cf[idx] = v + Res[idx];
        } else {
          Cf[idx] = v + Cf[idx];
        }
      }
    }
}

// ---------------------------------------------------------------- RoPE in place (q scaled 1/16) + V transpose -> vt (b,d,s)
__global__ __launch_bounds__(256) void rope_apply_kernel(u16* __restrict__ qkv,
                                                         const float* __restrict__ cosT,
                                                         const float* __restrict__ sinT,
                                                         u16* __restrict__ vt) {
  const int tok = blockIdx.x;
  const int b = tok >> 11, s = tok & 2047;
  u16* rowp = qkv + (size_t)tok * 2560;
  const float* ct = cosT + (size_t)tok * 128;
  const float* st = sinT + (size_t)tok * 128;
  for (int p = threadIdx.x; p < 1024; p += 256) {
    const int h = p >> 7, j = p & 127;
    u16* e = rowp + h * 256 + j;
    const float x1 = b2f(e[0]), x2 = b2f(e[128]);
    const float c = ct[j], sn = st[j];
    e[0]   = f2b((x1 * c - x2 * sn) * 0.0625f);
    e[128] = f2b((x2 * c + x1 * sn) * 0.0625f);
  }
  if (threadIdx.x < 128) {
    const int j = threadIdx.x;
    u16* e = rowp + 2048 + j;
    const float x1 = b2f(e[0]), x2 = b2f(e[128]);
    const float c = ct[j], sn = st[j];
    e[0]   = f2b(x1 * c - x2 * sn);
    e[128] = f2b(x2 * c + x1 * sn);
  }
  {
    const int d = threadIdx.x;
    vt[((size_t)b * HD_ + d) * SEQ + s] = rowp[2304 + d];
  }
}

// ---------------------------------------------------------------- row softmax, in place, 2048-wide bf16 rows
__global__ __launch_bounds__(256) void softmax_kernel(u16* __restrict__ Sb) {
  const int row = blockIdx.x;
  u16* rp = Sb + (size_t)row * 2048 + threadIdx.x * 8;
  const u16x8 t = *(const u16x8*)rp;
  float v[8];
#pragma unroll
  for (int j = 0; j < 8; ++j) v[j] = b2f(t[j]);
  float m = v[0];
#pragma unroll
  for (int j = 1; j < 8; ++j) m = fmaxf(m, v[j]);
  m = wmax(m);
  __shared__ float redm[4], reds[4];
  const int wave = threadIdx.x >> 6, lane = threadIdx.x & 63;
  if (lane == 0) redm[wave] = m;
  __syncthreads();
  m = fmaxf(fmaxf(redm[0], redm[1]), fmaxf(redm[2], redm[3]));
  float s = 0.f;
#pragma unroll
  for (int j = 0; j < 8; ++j) { v[j] = __expf(v[j] - m); s += v[j]; }
  s = wsum(s);
  if (lane == 0) reds[wave] = s;
  __syncthreads();
  const float inv = 1.0f / (reds[0] + reds[1] + reds[2] + reds[3]);
  u16x8 o;
#pragma unroll
  for (int j = 0; j < 8; ++j) o[j] = f2b(v[j] * inv);
  *(u16x8*)rp = o;
}

// ---------------------------------------------------------------- launch
extern "C" void kernel_launch(void* const* d_in, const int* in_sizes, int n_in,
                              void* d_out, int out_size, void* d_ws, size_t ws_size,
                              hipStream_t stream) {
  const float* x     = (const float*)d_in[0];
  const int*   pos   = (const int*)d_in[1];
  const float* temb  = (const float*)d_in[2];
  const float* ln1w  = (const float*)d_in[3];
  const float* ln1tw = (const float*)d_in[4];
  const float* ln2w  = (const float*)d_in[5];
  const float* ln2tw = (const float*)d_in[6];
  const float* Wq    = (const float*)d_in[7];
  const float* Wk    = (const float*)d_in[8];
  const float* Wv    = (const float*)d_in[9];
  const float* Wo    = (const float*)d_in[10];
  const float* Wg    = (const float*)d_in[11];
  const float* Wu    = (const float*)d_in[12];
  const float* Wd    = (const float*)d_in[13];
  float* out = (float*)d_out;      // fp32 output

  char* ws = (char*)d_ws;
  // ---- workspace layout (bytes); REQUIRED = 241,238,016 (230.06 MiB, proven)
  constexpr size_t OFF_SF1  = 0;
  constexpr size_t OFF_SF2  = 32768;
  constexpr size_t OFF_COS  = 65536;
  constexpr size_t OFF_SIN  = 4259840;
  constexpr size_t OFF_WQKV = 8454144;
  constexpr size_t OFF_WO   = 18939904;
  constexpr size_t OFF_WG   = 27328512;
  constexpr size_t OFF_WU   = 60882944;
  constexpr size_t OFF_WD   = 94437376;
  constexpr size_t OFF_H    = 127991808;
  constexpr size_t OFF_QKV  = 161546240;   // MLP phase: inter (67.1MB, M=4096 chunk) aliases qkv+vt+ctx
  constexpr size_t OFF_VT   = 203489280;
  constexpr size_t OFF_CTX  = 207683584;
  constexpr size_t REQUIRED = 241238016;

  float* sf1 = (float*)(ws + OFF_SF1);
  float* sf2 = (float*)(ws + OFF_SF2);
  float* cosT = (float*)(ws + OFF_COS);
  float* sinT = (float*)(ws + OFF_SIN);
  u16* wqkv = (u16*)(ws + OFF_WQKV);
  u16* wo   = (u16*)(ws + OFF_WO);
  u16* wg   = (u16*)(ws + OFF_WG);
  u16* wu   = (u16*)(ws + OFF_WU);
  u16* wd   = (u16*)(ws + OFF_WD);
  u16* hbuf = (u16*)(ws + OFF_H);
  u16* qkv  = (u16*)(ws + OFF_QKV);
  u16* vt   = (u16*)(ws + OFF_VT);
  u16* ctx  = (u16*)(ws + OFF_CTX);
  u16* inter = (u16*)(ws + OFF_QKV);       // 4096 x 8192 bf16 chunk
  u16* Sbuf = (u16*)d_out;                 // d_out (67.1 MB) dead until step 6

  if (ws_size < REQUIRED) return;

  auto cvt = [&](const float* s, u16* d, size_t n) {
    int n4 = (int)(n / 4);
    cvt_kernel<<<(n4 + 255) / 256, 256, 0, stream>>>(s, d, n4);
  };

  // 0) all weights -> bf16 once
  cvt(Wq, wqkv,                      (size_t)2048 * HID);
  cvt(Wk, wqkv + (size_t)2048 * HID, (size_t)256 * HID);
  cvt(Wv, wqkv + (size_t)2304 * HID, (size_t)256 * HID);
  cvt(Wo, wo, (size_t)HID * HID);
  cvt(Wg, wg, (size_t)INTER_ * HID);
  cvt(Wu, wu, (size_t)INTER_ * HID);
  cvt(Wd, wd, (size_t)HID * INTER_);

  // 1) adaptive scales + rope tables
  scale_kernel<<<(2 * BB * HID) / 4, 256, 0, stream>>>(temb, ln1w, ln1tw, ln2w, ln2tw, sf1, sf2);
  rope_table_kernel<<<(BB * SEQ * 128) / 256, 256, 0, stream>>>(pos, cosT, sinT);

  // 2) norm1 -> h (bf16)
  rmsnorm_kernel<<<BB * SEQ, 256, 0, stream>>>(x, sf1, hbuf);

  // 3) qkv = h @ Wqkv^T  (256^2 kernel: M=8192, N=2560, K=2048)
  gemm256<0><<<dim3(32, 10), 512, 0, stream>>>(hbuf, wqkv, nullptr, qkv, HID, HID, HID, 2560);

  // 4) rope in place (q scaled 1/16), v -> vt
  rope_apply_kernel<<<BB * SEQ, 256, 0, stream>>>(qkv, cosT, sinT, vt);

  // 5) attention per batch: all 8 heads per launch (Sbuf = d_out scratch)
  for (int b = 0; b < BB; ++b) {
    const u16* qb = qkv + (size_t)b * SEQ * 2560;          // head h at +h*256
    const u16* kb = qb + 2048;
    const u16* vb = vt + (size_t)b * HD_ * SEQ;
    u16* cb = ctx + (size_t)b * SEQ * HID;                 // head h at +h*256
    gemm_bt<0><<<dim3(16, 16, 8), 256, 0, stream>>>(
        qb, kb, nullptr, Sbuf, HD_, 2560, 2560, SEQ, (size_t)HD_, (size_t)SEQ * SEQ);
    softmax_kernel<<<NQH * SEQ, 256, 0, stream>>>(Sbuf);
    gemm_bt<0><<<dim3(16, 2, 8), 256, 0, stream>>>(
        Sbuf, vb, nullptr, cb, SEQ, SEQ, SEQ, HID, (size_t)SEQ * SEQ, (size_t)HD_);
  }

  // 6) x2 = ctx @ Wo^T + x -> out (fp32; 256^2 kernel)
  gemm256<2><<<dim3(32, 8), 512, 0, stream>>>(ctx, wo, x, out, HID, HID, HID, HID);

  // 7) norm2 -> h (reads fp32 x2)
  rmsnorm_kernel<<<BB * SEQ, 256, 0, stream>>>(out, sf2, hbuf);

  // 8) MLP, 2 chunks of M=4096 (inter aliases dead qkv/vt/ctx); g/u on 256^2 kernel
  constexpr int MC = BB * SEQ / 2;   // 4096
  for (int c = 0; c < 2; ++c) {
    const u16* hA = hbuf + (size_t)c * MC * HID;
    float* outC = out + (size_t)c * MC * HID;
    gemm256<0><<<dim3(MC / 256, INTER_ / 256), 512, 0, stream>>>(hA, wg, nullptr, inter, HID, HID, HID, INTER_);
    gemm256<1><<<dim3(MC / 256, INTER_ / 256), 512, 0, stream>>>(hA, wu, nullptr, inter, HID, HID, HID, INTER_);
    gemm_bt<3><<<dim3(MC / 128, HID / 128), 256, 0, stream>>>(inter, wd, nullptr, outC, INTER_, INTER_, INTER_, HID, 0, 0);
  }

  (void)in_sizes; (void)n_in; (void)out_size;
}